// Round 8
// baseline (1480.565 us; speedup 1.0000x reference)
//
#include <hip/hip_runtime.h>
#include <stdint.h>

typedef unsigned short u16;
typedef unsigned int   u32;
typedef __attribute__((ext_vector_type(8))) short short8;
typedef __attribute__((ext_vector_type(4))) short short4v;
typedef __attribute__((ext_vector_type(4))) float float4v;
typedef __attribute__((ext_vector_type(4))) u32   uint4v;

#define B_  4
#define T_  4096
#define C_  1024
#define H_  16
#define G_  16
#define GS_ 256
#define NC_ 64

static __device__ __forceinline__ u16 f2bf(float f){
  union{float f; u32 u;} c; c.f = f;
  return (u16)((c.u + 0x7fffu + ((c.u >> 16) & 1u)) >> 16);
}
static __device__ __forceinline__ float bf2f(u16 u){
  union{u32 u; float f;} c; c.u = ((u32)u) << 16; return c.f;
}
static __device__ __forceinline__ void gload16(const void* g, void* l){
  __builtin_amdgcn_global_load_lds((__attribute__((address_space(1))) void*)g,
                                   (__attribute__((address_space(3))) void*)l, 16, 0, 0);
}
// rotary on 4 bf16 pairs: out = (-x1*cos, x0*sin); Sp = S + pos*64, i0 = pair index base
static __device__ __forceinline__ short8 rot8(short8 v, const float* Sp, int i0){
  union{ short8 s; u32 u[4]; } a, o; a.s = v;
  #pragma unroll
  for(int p = 0; p < 4; p++){
    float e0 = bf2f((u16)(a.u[p] & 0xffffu));
    float e1 = bf2f((u16)(a.u[p] >> 16));
    float sn = Sp[i0 + p], cs = Sp[32 + i0 + p];
    o.u[p] = (u32)f2bf(-e1 * cs) | ((u32)f2bf(e0 * sn) << 16);
  }
  return o.s;
}

// ---------------- merged init: fp32->bf16 for x/w_attn/w_proj + sinusoid table ----------------
__global__ __launch_bounds__(256) void init_kernel(const float* __restrict__ x,
    const float* __restrict__ wa, const float* __restrict__ wp,
    u16* __restrict__ xb, u16* __restrict__ wab, u16* __restrict__ wpb,
    float* __restrict__ S)
{
  const int bid = blockIdx.x;
  if(bid < 20480){
    int i = bid * 256 + threadIdx.x;           // float4 index in [0, 5242880)
    const float* s; u16* d; int off;
    if(i < 4194304){ s = x; d = xb; off = i; }
    else if(i < 4980736){ s = wa; d = wab; off = i - 4194304; }
    else { s = wp; d = wpb; off = i - 4980736; }
    float4v v = *(const float4v*)(s + (size_t)off * 4);
    short4v o;
    o.x = (short)f2bf(v.x); o.y = (short)f2bf(v.y);
    o.z = (short)f2bf(v.z); o.w = (short)f2bf(v.w);
    *(short4v*)(d + (size_t)off * 4) = o;
  } else {
    int pos = (bid - 20480) * 4 + (threadIdx.x >> 6);
    int d = threadIdx.x & 63;
    if(pos < 316){
      int j = d >> 1;
      float div = __expf((float)(2 * j) * (-0.14391156831212787f)); // -ln(10000)/64
      float ang = (float)pos * div;
      S[pos * 64 + d] = (d & 1) ? cosf(ang) : sinf(ang);
    }
  }
}

// ================= BK=32 256x256 GEMM, 64KB LDS -> 2 blocks/CU =================
// C[M,N] = A[M,K]*B[N,K]^T + bias. Same per-K instruction density as the proven BK=64
// 8-phase kernel; LDS halved for occupancy-2 cross-block stall hiding at shallow K.
// FIFO-derived counted waits: vmcnt(3) mid-tile, vmcnt(1) end-tile (never 0 in loop).
// MODE 1: bf16 out; V-col blocks (col0>=2048) also write pre-swizzled vt slots.
// MODE 2: fp32 out; A read from blocked-y layout [b*16+g][h][256][64].
template<int MODE>
__global__ __launch_bounds__(512, 4) void gemm8p(const u16* __restrict__ A,
    const u16* __restrict__ Bm, const float* __restrict__ bias,
    void* __restrict__ Cv, u16* __restrict__ vtout, int M, int N, int K, int nbn)
{
  __shared__ u16 sA[2][2][128][32];   // [dbuf][mh-plane][plane-row][32]  32 KB
  __shared__ u16 sB[2][256][32];      // [dbuf][row][32]                  32 KB
  const int tid = threadIdx.x;
  const int lane = tid & 63, w = tid >> 6;
  const int l15 = lane & 15, l4 = lane >> 4;
  const int wr = w >> 2, wc = w & 3;

  const int cpx = gridDim.x >> 3;
  const int bid = blockIdx.x;
  const int swz = (bid & 7) * cpx + (bid >> 3);
  const int bm = swz / nbn, bn = swz - bm * nbn;
  const int row0 = bm * 256, col0 = bn * 256;

  float4v acc[8][4];
  #pragma unroll
  for(int m = 0; m < 8; m++)
    #pragma unroll
    for(int n = 0; n < 4; n++) acc[m][n] = (float4v){0.f, 0.f, 0.f, 0.f};

  // A quarter-plane stage: 128 rows {wrh*128 + mh*64 + rloc}, 1 gload/thread.
  // plane row pr = tid>>2, granule s0 = tid&3; pre-swizzled source granule.
  auto stageA = [&](int q, int mh, int ktOff){
    int pr = tid >> 2;
    int s0 = tid & 3;
    int trow = ((pr >> 6) << 7) + mh * 64 + (pr & 63);
    int ss = s0 ^ ((pr >> 1) & 3);
    const u16* src;
    if(MODE == 2){
      int bg = (row0 + trow) >> 8;
      int hh = ktOff >> 6;
      int coff = (ktOff & 63) + ss * 8;
      src = A + ((size_t)(bg * 16 + hh)) * 16384 + (size_t)(trow & 255) * 64 + coff;
    } else {
      src = A + (size_t)(row0 + trow) * K + ktOff + ss * 8;
    }
    gload16(src, &sA[q][mh][w * 16][0]);
  };
  // B half stage: 256 rows x 32, 2 gloads/thread
  auto stageB = [&](int q, int ktOff){
    #pragma unroll
    for(int l = 0; l < 2; l++){
      int r = w * 32 + l * 16 + (lane >> 2);
      int ss = (lane & 3) ^ ((r >> 1) & 3);
      gload16(Bm + (size_t)(col0 + r) * K + ktOff + ss * 8,
              &sB[q][w * 32 + l * 16][0]);
    }
  };
  auto ldsReadA = [&](int d, int mh, short8* af){
    #pragma unroll
    for(int i = 0; i < 4; i++){
      int pr = wr * 64 + i * 16 + l15;
      int slot = l4 ^ ((pr >> 1) & 3);
      af[i] = *(const short8*)&sA[d][mh][pr][slot * 8];
    }
  };
  auto ldsReadB = [&](int d, short8* bf){
    #pragma unroll
    for(int i = 0; i < 4; i++){
      int r = wc * 64 + i * 16 + l15;
      int slot = l4 ^ ((r >> 1) & 3);
      bf[i] = *(const short8*)&sB[d][r][slot * 8];
    }
  };
  auto mfma16 = [&](int mh, short8* af, short8* bf){
    __builtin_amdgcn_s_setprio(1);
    #pragma unroll
    for(int i = 0; i < 4; i++)
      #pragma unroll
      for(int n = 0; n < 4; n++)
        acc[mh * 4 + i][n] = __builtin_amdgcn_mfma_f32_16x16x32_bf16(af[i], bf[n], acc[mh * 4 + i][n], 0, 0, 0);
    __builtin_amdgcn_s_setprio(0);
  };

  // prologue: tile 0 into buf 0 (FIFO: Amh0, B, Amh1)
  stageA(0, 0, 0);
  stageB(0, 0);
  stageA(0, 1, 0);
  asm volatile("s_waitcnt vmcnt(0)" ::: "memory");
  __builtin_amdgcn_s_barrier();

  const int nT = K >> 5;
  for(int t = 0; t < nT; t++){
    const int p = t & 1, q = p ^ 1;
    const int ktN = (t + 1) << 5;
    const bool pf = (t + 1 < nT);
    short8 af[4], bf[4];

    // ph1: mh0 frags + full B; prefetch Amh0+B of next tile
    ldsReadA(p, 0, af); ldsReadB(p, bf);
    if(pf){ stageA(q, 0, ktN); stageB(q, ktN); }
    __builtin_amdgcn_s_barrier();
    mfma16(0, af, bf);
    if(pf) asm volatile("s_waitcnt vmcnt(3)" ::: "memory");  // Amh1(cur) landed
    else   asm volatile("s_waitcnt vmcnt(0)" ::: "memory");
    __builtin_amdgcn_s_barrier();

    // ph2: mh1 frags (bf reused); prefetch Amh1 of next tile
    ldsReadA(p, 1, af);
    if(pf) stageA(q, 1, ktN);
    __builtin_amdgcn_s_barrier();
    mfma16(1, af, bf);
    if(pf) asm volatile("s_waitcnt vmcnt(1)" ::: "memory");  // Amh0+B(next) landed
    __builtin_amdgcn_s_barrier();
  }

  // ---- epilogue ----
  #pragma unroll
  for(int m = 0; m < 8; m++){
    #pragma unroll
    for(int n = 0; n < 4; n++){
      int col = col0 + wc * 64 + n * 16 + l15;
      float bv = bias[col];
      #pragma unroll
      for(int j = 0; j < 4; j++){
        int row = row0 + wr * 128 + m * 16 + l4 * 4 + j;
        float v = acc[m][n][j] + bv;
        acc[m][n][j] = v;
        if(MODE == 1) ((u16*)Cv)[(size_t)row * N + col] = f2bf(v);
        else          ((float*)Cv)[(size_t)row * N + col] = v;
      }
    }
  }
  // fused vt write: V-col blocks cover exactly one (b,g) x 4 heads
  if(MODE == 1 && col0 >= 2048){
    const int b = row0 >> 12, g = (row0 >> 8) & 15;
    const int h = ((col0 - 2048) >> 6) + wc;
    u32* vbase = (u32*)(vtout + (((size_t)(b * 16 + g)) * 16 + h) * 16384);
    #pragma unroll
    for(int n = 0; n < 4; n++){
      int d = n * 16 + l15;
      #pragma unroll
      for(int m = 0; m < 8; m++){
        int kb = (wr * 128 + m * 16 + l4 * 4) >> 2;   // k>>2 (j<4)
        int col2 = (kb ^ (d & 7)) << 1;
        u32 lo = (u32)f2bf(acc[m][n][0]) | ((u32)f2bf(acc[m][n][1]) << 16);
        u32 hi = (u32)f2bf(acc[m][n][2]) | ((u32)f2bf(acc[m][n][3]) << 16);
        vbase[d * 128 + col2]     = lo;
        vbase[d * 128 + col2 + 1] = hi;
      }
    }
  }
}

// ---------------- cluster assign softmax + ck (rotated) / cv (transposed, PRE-SWIZZLED) ----------------
// logits from bf16 xb; weights/accum fp32.
__global__ __launch_bounds__(256) void cluster_kernel(
    const u16* __restrict__ xb, const float* __restrict__ wasn,
    const u16* __restrict__ qkv, const float* __restrict__ S,
    u16* __restrict__ ckr, u16* __restrict__ vct)
{
  const int bc = blockIdx.x;
  const int c = bc & 63, b = bc >> 6;
  const int tid = threadIdx.x;
  const int lane = tid & 63, wv = tid >> 6;
  __shared__ float wgt[64];

  const u16* xrow = xb + ((size_t)b * T_ + c * 64) * C_;
  float4v wa4[4];
  #pragma unroll
  for(int ch = 0; ch < 4; ch++)
    wa4[ch] = *(const float4v*)(wasn + c * C_ + ch * 256 + lane * 4);

  for(int it = 0; it < 16; it++){
    int t = it * 4 + wv;
    const u16* xr = xrow + (size_t)t * C_;
    float p = 0.f;
    #pragma unroll
    for(int ch = 0; ch < 4; ch++){
      short4v xv = *(const short4v*)(xr + ch * 256 + lane * 4);
      p += bf2f((u16)xv.x) * wa4[ch].x + bf2f((u16)xv.y) * wa4[ch].y
         + bf2f((u16)xv.z) * wa4[ch].z + bf2f((u16)xv.w) * wa4[ch].w;
    }
    p += __shfl_down(p, 32); p += __shfl_down(p, 16); p += __shfl_down(p, 8);
    p += __shfl_down(p, 4);  p += __shfl_down(p, 2);  p += __shfl_down(p, 1);
    if(lane == 0) wgt[t] = p;
  }
  __syncthreads();
  if(wv == 0){
    float v = wgt[lane];
    float mx = v;
    mx = fmaxf(mx, __shfl_xor(mx, 32)); mx = fmaxf(mx, __shfl_xor(mx, 16));
    mx = fmaxf(mx, __shfl_xor(mx, 8));  mx = fmaxf(mx, __shfl_xor(mx, 4));
    mx = fmaxf(mx, __shfl_xor(mx, 2));  mx = fmaxf(mx, __shfl_xor(mx, 1));
    float e = __expf(v - mx);
    float sm = e;
    sm += __shfl_xor(sm, 32); sm += __shfl_xor(sm, 16); sm += __shfl_xor(sm, 8);
    sm += __shfl_xor(sm, 4);  sm += __shfl_xor(sm, 2);  sm += __shfl_xor(sm, 1);
    wgt[lane] = e / sm;
  }
  __syncthreads();

  const int d0 = tid * 4;
  float ak[4] = {0, 0, 0, 0}, av[4] = {0, 0, 0, 0};
  const u16* krow = qkv + ((size_t)b * T_ + c * 64) * 3072 + C_ + d0;
  for(int t = 0; t < 64; t++){
    float wt = wgt[t];
    short4v kv = *(const short4v*)(krow + (size_t)t * 3072);
    short4v vv = *(const short4v*)(krow + (size_t)t * 3072 + C_);
    ak[0] += wt * bf2f((u16)kv.x); ak[1] += wt * bf2f((u16)kv.y);
    ak[2] += wt * bf2f((u16)kv.z); ak[3] += wt * bf2f((u16)kv.w);
    av[0] += wt * bf2f((u16)vv.x); av[1] += wt * bf2f((u16)vv.y);
    av[2] += wt * bf2f((u16)vv.z); av[3] += wt * bf2f((u16)vv.w);
  }
  const int dh = d0 & 63, i0 = dh >> 1;
  const float* Sp = S + c * 64;
  float s0 = Sp[i0],     c0 = Sp[32 + i0];
  float s1 = Sp[i0 + 1], c1 = Sp[32 + i0 + 1];
  short4v ck4;
  ck4.x = (short)f2bf(-ak[1] * c0); ck4.y = (short)f2bf(ak[0] * s0);
  ck4.z = (short)f2bf(-ak[3] * c1); ck4.w = (short)f2bf(ak[2] * s1);
  *(short4v*)(ckr + ((size_t)b * NC_ + c) * C_ + d0) = ck4;
  // cv transposed + pre-swizzled: elem(d,c) -> [d][ ((c>>2)^(d&7))*4 + (c&3) ]
  const int h = d0 >> 6;
  u16* vctb = vct + ((size_t)b * H_ + h) * 4096;
  #pragma unroll
  for(int i = 0; i < 4; i++){
    int d = dh + i;
    int col = ((c >> 2) ^ (d & 7)) * 4 + (c & 3);
    vctb[d * 64 + col] = f2bf(av[i]);
  }
}

// ====== attention v5: swapped QK^T, P in registers, FULL-K PV, causal-structure skips ======
// 1024 blocks (b,g,h), 8 waves; wave w owns q-frags w and 15-w.
__global__ __launch_bounds__(512, 4) void attn5_kernel(
    const u16* __restrict__ qkv, const u16* __restrict__ ckr,
    const u16* __restrict__ vct, u16* __restrict__ vt,
    const float* __restrict__ S)
{
  const int bid = blockIdx.x;
  const int h = bid & 15, g = (bid >> 4) & 15, b = bid >> 8;
  const int tid = threadIdx.x;
  const int lane = tid & 63, wv = tid >> 6;
  const int l15 = lane & 15, l4 = lane >> 4;
  const int rows0 = wv, rows1 = 15 - wv;

  __shared__ u16 SH[36864];          // 72 KB
  u16* Ksh = SH;                     // [256][64] u16, 16B-granule swz ^(row&7)
  u16* Vsh = SH + 16384;             // [64][256] u16, 8B-granule swz ^(d&7)
  u16* Vcl = SH + 32768;             // [64][64]  u16, 8B-granule swz ^(d&7)

  const size_t tok0 = (size_t)b * T_ + (size_t)g * GS_;
  u16* vslot = vt + (((size_t)b * 16 + g) * 16 + h) * 16384;

  // ---- stage Vsh + Vcl via gload16 (global layouts are pre-swizzled) ----
  {
    #pragma unroll
    for(int c = 0; c < 4; c++)
      gload16(vslot + (c * 512 + tid) * 8, Vsh + c * 4096 + wv * 512);
    gload16(vct + ((size_t)b * H_ + h) * 4096 + tid * 8, Vcl + wv * 512);
  }
  // ---- stage Ksh: global -> reg -> rotary -> swizzled LDS ----
  {
    const u16* kg = qkv + tok0 * 3072 + C_ + h * 64;
    #pragma unroll
    for(int c = 0; c < 4; c++){
      int idx = c * 512 + tid;
      int row = idx >> 3;
      int s0  = idx & 7;
      short8 v = *(const short8*)(kg + (size_t)row * 3072 + s0 * 8);
      short8 rv = rot8(v, S + (g * 4 + row) * 64, s0 * 4);
      *(short8*)(Ksh + row * 64 + (s0 ^ (row & 7)) * 8) = rv;
    }
  }
  // ---- Q frags (rotated) ----
  short8 qa[2][2];
  #pragma unroll
  for(int f = 0; f < 2; f++){
    int rf = f ? rows1 : rows0;
    int qr = rf * 16 + l15;
    const u16* qp = qkv + (tok0 + qr) * 3072 + h * 64;
    #pragma unroll
    for(int kk = 0; kk < 2; kk++)
      qa[f][kk] = rot8(*(const short8*)(qp + kk * 32 + l4 * 8),
                       S + qr * 64, kk * 16 + l4 * 4);
  }
  __syncthreads();   // drains vmcnt+lgkm before any wave reads LDS

  float4v o[2][4], osum[2];
  float mst[2];
  #pragma unroll
  for(int f = 0; f < 2; f++){
    osum[f] = (float4v){0, 0, 0, 0};
    mst[f] = -1e30f;
    #pragma unroll
    for(int n = 0; n < 4; n++) o[f][n] = (float4v){0, 0, 0, 0};
  }

  // softmax update on S^T frag: st[n][r] = S[q=l15][k'=n*16+l4*4+r]
  auto sm_update = [&](int f, float4v* st){
    float mx = st[0][0];
    #pragma unroll
    for(int n = 0; n < 4; n++)
      #pragma unroll
      for(int r = 0; r < 4; r++) mx = fmaxf(mx, st[n][r]);
    mx = fmaxf(mx, __shfl_xor(mx, 16));
    mx = fmaxf(mx, __shfl_xor(mx, 32));
    float mOld = mst[f];
    if(!__all(mx <= mOld)){
      float mn = fmaxf(mOld, mx);
      float rsc = __expf(mOld - mn);
      mst[f] = mn;
      float r0 = __shfl(rsc, l4 * 4 + 0);
      float r1 = __shfl(rsc, l4 * 4 + 1);
      float r2 = __shfl(rsc, l4 * 4 + 2);
      float r3 = __shfl(rsc, l4 * 4 + 3);
      #pragma unroll
      for(int n = 0; n < 4; n++){
        o[f][n][0] *= r0; o[f][n][1] *= r1; o[f][n][2] *= r2; o[f][n][3] *= r3;
      }
      osum[f][0] *= r0; osum[f][1] *= r1; osum[f][2] *= r2; osum[f][3] *= r3;
    }
    float mm = mst[f];
    #pragma unroll
    for(int n = 0; n < 4; n++)
      #pragma unroll
      for(int r = 0; r < 4; r++) st[n][r] = __expf(st[n][r] - mm);
  };

  // FULL-K PV: pair of 16-k P-blocks per MFMA; kbpMax in {1,2} skips all-masked pairs.
  auto pv = [&](int f, float4v* st, const u16* vb, int vstride, int granBase, int kbpMax){
    #pragma unroll
    for(int kbp = 0; kbp < 2; kbp++){
      if(kbp >= kbpMax) continue;
      union{ short8 s; u32 u[4]; } pa;
      pa.u[0] = (u32)f2bf(st[2*kbp][0])   | ((u32)f2bf(st[2*kbp][1]) << 16);
      pa.u[1] = (u32)f2bf(st[2*kbp][2])   | ((u32)f2bf(st[2*kbp][3]) << 16);
      pa.u[2] = (u32)f2bf(st[2*kbp+1][0]) | ((u32)f2bf(st[2*kbp+1][1]) << 16);
      pa.u[3] = (u32)f2bf(st[2*kbp+1][2]) | ((u32)f2bf(st[2*kbp+1][3]) << 16);
      union{ short8 s; u32 u[4]; } on;
      on.u[0] = 0x3F803F80u; on.u[1] = 0x3F803F80u;
      on.u[2] = 0x3F803F80u; on.u[3] = 0x3F803F80u;
      __builtin_amdgcn_s_setprio(1);
      osum[f] = __builtin_amdgcn_mfma_f32_16x16x32_bf16(pa.s, on.s, osum[f], 0, 0, 0);
      #pragma unroll
      for(int dn = 0; dn < 4; dn++){
        int d = dn * 16 + l15;
        int gA = (granBase + (2*kbp) * 4 + l4) ^ (l15 & 7);
        int gB = (granBase + (2*kbp+1) * 4 + l4) ^ (l15 & 7);
        short4v vA = *(const short4v*)(vb + d * vstride + gA * 4);
        short4v vB = *(const short4v*)(vb + d * vstride + gB * 4);
        union{ short8 s; u32 u[4]; } vf;
        vf.u[0] = (u32)(u16)vA.x | ((u32)(u16)vA.y << 16);
        vf.u[1] = (u32)(u16)vA.z | ((u32)(u16)vA.w << 16);
        vf.u[2] = (u32)(u16)vB.x | ((u32)(u16)vB.y << 16);
        vf.u[3] = (u32)(u16)vB.z | ((u32)(u16)vB.w << 16);
        o[f][dn] = __builtin_amdgcn_mfma_f32_16x16x32_bf16(pa.s, vf.s, o[f][dn], 0, 0, 0);
      }
      __builtin_amdgcn_s_setprio(0);
    }
  };

  // ---- cluster tile (g>0): S^T rows = clusters, mask cluster >= g*4 ----
  if(g > 0){
    const int climit = g * 4;
    const int nMaxC = (climit - 1) >> 4;
    const int kbpMaxC = (nMaxC >> 1) + 1;
    #pragma unroll
    for(int f = 0; f < 2; f++){
      float4v st[4];
      #pragma unroll
      for(int n = 0; n < 4; n++) st[n] = (float4v){0, 0, 0, 0};
      #pragma unroll
      for(int kk = 0; kk < 2; kk++){
        __builtin_amdgcn_s_setprio(1);
        #pragma unroll
        for(int n = 0; n < 4; n++){
          if(n > nMaxC) continue;
          short8 kf = *(const short8*)(ckr + ((size_t)b * NC_ + n * 16 + l15) * C_
                                       + h * 64 + kk * 32 + l4 * 8);
          st[n] = __builtin_amdgcn_mfma_f32_16x16x32_bf16(kf, qa[f][kk], st[n], 0, 0, 0);
        }
        __builtin_amdgcn_s_setprio(0);
      }
      #pragma unroll
      for(int n = 0; n < 4; n++)
        #pragma unroll
        for(int r = 0; r < 4; r++){
          int col = n * 16 + l4 * 4 + r;
          st[n][r] = (col >= climit) ? -1e30f : st[n][r] * 0.125f;
        }
      sm_update(f, st);
      pv(f, st, Vcl, 64, 0, kbpMaxC);
    }
  }

  // ---- local causal tiles: K from Ksh, V from Vsh ----
  const int ktA = rows0 >> 2, ktB = rows1 >> 2;
  for(int kt = 0; kt <= ktB; kt++){
    #pragma unroll
    for(int f = 0; f < 2; f++){
      int rf = f ? rows1 : rows0;
      if(kt > (f ? ktB : ktA)) continue;
      const bool diag = (kt == (rf >> 2));
      const int nMax = diag ? (rf & 3) : 3;
      const int kbpMax = diag ? (((rf & 3) >> 1) + 1) : 2;
      float4v st[4];
      #pragma unroll
      for(int n = 0; n < 4; n++) st[n] = (float4v){0, 0, 0, 0};
      #pragma unroll
      for(int kk = 0; kk < 2; kk++){
        __builtin_amdgcn_s_setprio(1);
        #pragma unroll
        for(int n = 0; n < 4; n++){
          if(n > nMax) continue;
          int krow = kt * 64 + n * 16 + l15;
          int slot = (kk * 4 + l4) ^ (krow & 7);
          short8 kf = *(const short8*)(Ksh + krow * 64 + slot * 8);
          st[n] = __builtin_amdgcn_mfma_f32_16x16x32_bf16(kf, qa[f][kk], st[n], 0, 0, 0);
        }
        __builtin_amdgcn_s_setprio(0);
      }
      #pragma unroll
      for(int n = 0; n < 4; n++)
        #pragma unroll
        for(int r = 0; r < 4; r++){
          int col = kt * 64 + n * 16 + l4 * 4 + r;
          int q   = rf * 16 + l15;
          st[n][r] = (col > q) ? -1e30f : st[n][r] * 0.125f;
        }
      sm_update(f, st);
      pv(f, st, Vsh, 256, kt * 16, kbpMax);
    }
  }

  // ---- epilogue: normalize, write blocked y into OWN vt slot (contiguous 32KB) ----
  #pragma unroll
  for(int f = 0; f < 2; f++){
    int rf = f ? rows1 : rows0;
    #pragma unroll
    for(int r = 0; r < 4; r++){
      float inv = 1.0f / osum[f][r];
      int kq = rf * 16 + l4 * 4 + r;
      #pragma unroll
      for(int n = 0; n < 4; n++)
        vslot[kq * 64 + n * 16 + l15] = f2bf(o[f][n][r] * inv);
    }
  }
}

// ---------------- launcher ----------------
extern "C" void kernel_launch(void* const* d_in, const int* in_sizes, int n_in,
                              void* d_out, int out_size, void* d_ws, size_t ws_size,
                              hipStream_t stream)
{
  const float* x      = (const float*)d_in[0];
  const float* w_attn = (const float*)d_in[1];
  const float* b_attn = (const float*)d_in[2];
  const float* w_proj = (const float*)d_in[3];
  const float* b_proj = (const float*)d_in[4];
  const float* wasn   = (const float*)d_in[5];
  float* out = (float*)d_out;
  char* ws = (char*)d_ws;

  u16* qkv  = (u16*)(ws);                    // 100,663,296  bf16 (B,T,3C) RAW (unrotated)
  u16* xb   = (u16*)(ws + 100663296);        //  33,554,432  bf16 x
  u16* vt   = (u16*)(ws + 134217728);        //  33,554,432  [b,g,h] slots: V^T pre-swz, then y-blocked
  u16* wab  = (u16*)(ws + 167772160);        //   6,291,456
  u16* wpb  = (u16*)(ws + 174063616);        //   2,097,152
  u16* ckr  = (u16*)(ws + 176160768);        //     524,288  rotated cluster keys
  u16* vct  = (u16*)(ws + 176685056);        //     524,288  transposed cluster values (pre-swz)
  float* st = (float*)(ws + 177209344);      //      80,896  sinusoid table
  if(ws_size < 177290240) return;

  init_kernel<<<20559, 256, 0, stream>>>(x, w_attn, w_proj, xb, wab, wpb, st);
  gemm8p<1><<<768, 512, 0, stream>>>(xb, wab, b_attn, (void*)qkv, vt, 16384, 3072, 1024, 12);
  cluster_kernel<<<256, 256, 0, stream>>>(xb, wasn, qkv, st, ckr, vct);
  attn5_kernel<<<1024, 512, 0, stream>>>(qkv, ckr, vct, vt, st);
  gemm8p<2><<<256, 512, 0, stream>>>(vt, wpb, b_proj, (void*)out, nullptr, 16384, 1024, 1024, 4);
}

// Round 9
// 266.717 us; speedup vs baseline: 5.5511x; 5.5511x over previous
//
#include <hip/hip_runtime.h>
#include <stdint.h>

typedef unsigned short u16;
typedef unsigned int   u32;
typedef __attribute__((ext_vector_type(8))) short short8;
typedef __attribute__((ext_vector_type(4))) short short4v;
typedef __attribute__((ext_vector_type(4))) float float4v;
typedef __attribute__((ext_vector_type(4))) u32   uint4v;

#define B_  4
#define T_  4096
#define C_  1024
#define H_  16
#define G_  16
#define GS_ 256
#define NC_ 64

static __device__ __forceinline__ u16 f2bf(float f){
  union{float f; u32 u;} c; c.f = f;
  return (u16)((c.u + 0x7fffu + ((c.u >> 16) & 1u)) >> 16);
}
static __device__ __forceinline__ float bf2f(u16 u){
  union{u32 u; float f;} c; c.u = ((u32)u) << 16; return c.f;
}
static __device__ __forceinline__ void gload16(const void* g, void* l){
  __builtin_amdgcn_global_load_lds((__attribute__((address_space(1))) void*)g,
                                   (__attribute__((address_space(3))) void*)l, 16, 0, 0);
}
// rotary on 4 bf16 pairs: out = (-x1*cos, x0*sin); Sp = S + pos*64, i0 = pair index base
static __device__ __forceinline__ short8 rot8(short8 v, const float* Sp, int i0){
  union{ short8 s; u32 u[4]; } a, o; a.s = v;
  #pragma unroll
  for(int p = 0; p < 4; p++){
    float e0 = bf2f((u16)(a.u[p] & 0xffffu));
    float e1 = bf2f((u16)(a.u[p] >> 16));
    float sn = Sp[i0 + p], cs = Sp[32 + i0 + p];
    o.u[p] = (u32)f2bf(-e1 * cs) | ((u32)f2bf(e0 * sn) << 16);
  }
  return o.s;
}

// ---------------- merged init: fp32->bf16 for x/w_attn/w_proj + sinusoid table ----------------
__global__ __launch_bounds__(256) void init_kernel(const float* __restrict__ x,
    const float* __restrict__ wa, const float* __restrict__ wp,
    u16* __restrict__ xb, u16* __restrict__ wab, u16* __restrict__ wpb,
    float* __restrict__ S)
{
  const int bid = blockIdx.x;
  if(bid < 20480){
    int i = bid * 256 + threadIdx.x;           // float4 index in [0, 5242880)
    const float* s; u16* d; int off;
    if(i < 4194304){ s = x; d = xb; off = i; }
    else if(i < 4980736){ s = wa; d = wab; off = i - 4194304; }
    else { s = wp; d = wpb; off = i - 4980736; }
    float4v v = *(const float4v*)(s + (size_t)off * 4);
    short4v o;
    o.x = (short)f2bf(v.x); o.y = (short)f2bf(v.y);
    o.z = (short)f2bf(v.z); o.w = (short)f2bf(v.w);
    *(short4v*)(d + (size_t)off * 4) = o;
  } else {
    int pos = (bid - 20480) * 4 + (threadIdx.x >> 6);
    int d = threadIdx.x & 63;
    if(pos < 316){
      int j = d >> 1;
      float div = __expf((float)(2 * j) * (-0.14391156831212787f)); // -ln(10000)/64
      float ang = (float)pos * div;
      S[pos * 64 + d] = (d & 1) ? cosf(ang) : sinf(ang);
    }
  }
}

// ================= BK=32 256x256 GEMM, 64KB LDS =================
// __launch_bounds__(512, 1): do NOT cap registers (R8 lesson: (512,4) spilled the
// 128-float accumulator to scratch -> VGPR 64, 2.6GB scratch writes, 9x slowdown).
// With ~104 VGPRs and 64KB LDS, HW occupancy is 2 blocks/CU automatically
// (LDS: 128/64=2; VGPR: 16 waves x 104 = 1664 <= 2048).
// FIFO-derived counted waits: vmcnt(3) mid-tile, vmcnt(1) end-tile (never 0 in loop).
// MODE 1: bf16 out; V-col blocks (col0>=2048) also write pre-swizzled vt slots.
// MODE 2: fp32 out; A read from blocked-y layout [b*16+g][h][256][64].
template<int MODE>
__global__ __launch_bounds__(512, 1) void gemm8p(const u16* __restrict__ A,
    const u16* __restrict__ Bm, const float* __restrict__ bias,
    void* __restrict__ Cv, u16* __restrict__ vtout, int M, int N, int K, int nbn)
{
  __shared__ u16 sA[2][2][128][32];   // [dbuf][mh-plane][plane-row][32]  32 KB
  __shared__ u16 sB[2][256][32];      // [dbuf][row][32]                  32 KB
  const int tid = threadIdx.x;
  const int lane = tid & 63, w = tid >> 6;
  const int l15 = lane & 15, l4 = lane >> 4;
  const int wr = w >> 2, wc = w & 3;

  const int cpx = gridDim.x >> 3;
  const int bid = blockIdx.x;
  const int swz = (bid & 7) * cpx + (bid >> 3);
  const int bm = swz / nbn, bn = swz - bm * nbn;
  const int row0 = bm * 256, col0 = bn * 256;

  float4v acc[8][4];
  #pragma unroll
  for(int m = 0; m < 8; m++)
    #pragma unroll
    for(int n = 0; n < 4; n++) acc[m][n] = (float4v){0.f, 0.f, 0.f, 0.f};

  // A quarter-plane stage: 128 rows {wrh*128 + mh*64 + rloc}, 1 gload/thread.
  auto stageA = [&](int q, int mh, int ktOff){
    int pr = tid >> 2;
    int s0 = tid & 3;
    int trow = ((pr >> 6) << 7) + mh * 64 + (pr & 63);
    int ss = s0 ^ ((pr >> 1) & 3);
    const u16* src;
    if(MODE == 2){
      int bg = (row0 + trow) >> 8;
      int hh = ktOff >> 6;
      int coff = (ktOff & 63) + ss * 8;
      src = A + ((size_t)(bg * 16 + hh)) * 16384 + (size_t)(trow & 255) * 64 + coff;
    } else {
      src = A + (size_t)(row0 + trow) * K + ktOff + ss * 8;
    }
    gload16(src, &sA[q][mh][w * 16][0]);
  };
  // B half stage: 256 rows x 32, 2 gloads/thread
  auto stageB = [&](int q, int ktOff){
    #pragma unroll
    for(int l = 0; l < 2; l++){
      int r = w * 32 + l * 16 + (lane >> 2);
      int ss = (lane & 3) ^ ((r >> 1) & 3);
      gload16(Bm + (size_t)(col0 + r) * K + ktOff + ss * 8,
              &sB[q][w * 32 + l * 16][0]);
    }
  };
  auto ldsReadA = [&](int d, int mh, short8* af){
    #pragma unroll
    for(int i = 0; i < 4; i++){
      int pr = wr * 64 + i * 16 + l15;
      int slot = l4 ^ ((pr >> 1) & 3);
      af[i] = *(const short8*)&sA[d][mh][pr][slot * 8];
    }
  };
  auto ldsReadB = [&](int d, short8* bf){
    #pragma unroll
    for(int i = 0; i < 4; i++){
      int r = wc * 64 + i * 16 + l15;
      int slot = l4 ^ ((r >> 1) & 3);
      bf[i] = *(const short8*)&sB[d][r][slot * 8];
    }
  };
  auto mfma16 = [&](int mh, short8* af, short8* bf){
    __builtin_amdgcn_s_setprio(1);
    #pragma unroll
    for(int i = 0; i < 4; i++)
      #pragma unroll
      for(int n = 0; n < 4; n++)
        acc[mh * 4 + i][n] = __builtin_amdgcn_mfma_f32_16x16x32_bf16(af[i], bf[n], acc[mh * 4 + i][n], 0, 0, 0);
    __builtin_amdgcn_s_setprio(0);
  };

  // prologue: tile 0 into buf 0 (FIFO: Amh0, B, Amh1)
  stageA(0, 0, 0);
  stageB(0, 0);
  stageA(0, 1, 0);
  asm volatile("s_waitcnt vmcnt(0)" ::: "memory");
  __builtin_amdgcn_s_barrier();

  const int nT = K >> 5;
  for(int t = 0; t < nT; t++){
    const int p = t & 1, q = p ^ 1;
    const int ktN = (t + 1) << 5;
    const bool pf = (t + 1 < nT);
    short8 af[4], bf[4];

    // ph1: mh0 frags + full B; prefetch Amh0+B of next tile
    ldsReadA(p, 0, af); ldsReadB(p, bf);
    if(pf){ stageA(q, 0, ktN); stageB(q, ktN); }
    __builtin_amdgcn_s_barrier();
    mfma16(0, af, bf);
    if(pf) asm volatile("s_waitcnt vmcnt(3)" ::: "memory");  // Amh1(cur) landed
    else   asm volatile("s_waitcnt vmcnt(0)" ::: "memory");
    __builtin_amdgcn_s_barrier();

    // ph2: mh1 frags (bf reused); prefetch Amh1 of next tile
    ldsReadA(p, 1, af);
    if(pf) stageA(q, 1, ktN);
    __builtin_amdgcn_s_barrier();
    mfma16(1, af, bf);
    if(pf) asm volatile("s_waitcnt vmcnt(1)" ::: "memory");  // Amh0+B(next) landed
    __builtin_amdgcn_s_barrier();
  }

  // ---- epilogue ----
  #pragma unroll
  for(int m = 0; m < 8; m++){
    #pragma unroll
    for(int n = 0; n < 4; n++){
      int col = col0 + wc * 64 + n * 16 + l15;
      float bv = bias[col];
      #pragma unroll
      for(int j = 0; j < 4; j++){
        int row = row0 + wr * 128 + m * 16 + l4 * 4 + j;
        float v = acc[m][n][j] + bv;
        acc[m][n][j] = v;
        if(MODE == 1) ((u16*)Cv)[(size_t)row * N + col] = f2bf(v);
        else          ((float*)Cv)[(size_t)row * N + col] = v;
      }
    }
  }
  // fused vt write: V-col blocks cover exactly one (b,g) x 4 heads
  if(MODE == 1 && col0 >= 2048){
    const int b = row0 >> 12, g = (row0 >> 8) & 15;
    const int h = ((col0 - 2048) >> 6) + wc;
    u32* vbase = (u32*)(vtout + (((size_t)(b * 16 + g)) * 16 + h) * 16384);
    #pragma unroll
    for(int n = 0; n < 4; n++){
      int d = n * 16 + l15;
      #pragma unroll
      for(int m = 0; m < 8; m++){
        int kb = (wr * 128 + m * 16 + l4 * 4) >> 2;   // k>>2 (j<4)
        int col2 = (kb ^ (d & 7)) << 1;
        u32 lo = (u32)f2bf(acc[m][n][0]) | ((u32)f2bf(acc[m][n][1]) << 16);
        u32 hi = (u32)f2bf(acc[m][n][2]) | ((u32)f2bf(acc[m][n][3]) << 16);
        vbase[d * 128 + col2]     = lo;
        vbase[d * 128 + col2 + 1] = hi;
      }
    }
  }
}

// ---------------- cluster assign softmax + ck (rotated) / cv (transposed, PRE-SWIZZLED) ----------------
// logits from bf16 xb; weights/accum fp32.
__global__ __launch_bounds__(256) void cluster_kernel(
    const u16* __restrict__ xb, const float* __restrict__ wasn,
    const u16* __restrict__ qkv, const float* __restrict__ S,
    u16* __restrict__ ckr, u16* __restrict__ vct)
{
  const int bc = blockIdx.x;
  const int c = bc & 63, b = bc >> 6;
  const int tid = threadIdx.x;
  const int lane = tid & 63, wv = tid >> 6;
  __shared__ float wgt[64];

  const u16* xrow = xb + ((size_t)b * T_ + c * 64) * C_;
  float4v wa4[4];
  #pragma unroll
  for(int ch = 0; ch < 4; ch++)
    wa4[ch] = *(const float4v*)(wasn + c * C_ + ch * 256 + lane * 4);

  for(int it = 0; it < 16; it++){
    int t = it * 4 + wv;
    const u16* xr = xrow + (size_t)t * C_;
    float p = 0.f;
    #pragma unroll
    for(int ch = 0; ch < 4; ch++){
      short4v xv = *(const short4v*)(xr + ch * 256 + lane * 4);
      p += bf2f((u16)xv.x) * wa4[ch].x + bf2f((u16)xv.y) * wa4[ch].y
         + bf2f((u16)xv.z) * wa4[ch].z + bf2f((u16)xv.w) * wa4[ch].w;
    }
    p += __shfl_down(p, 32); p += __shfl_down(p, 16); p += __shfl_down(p, 8);
    p += __shfl_down(p, 4);  p += __shfl_down(p, 2);  p += __shfl_down(p, 1);
    if(lane == 0) wgt[t] = p;
  }
  __syncthreads();
  if(wv == 0){
    float v = wgt[lane];
    float mx = v;
    mx = fmaxf(mx, __shfl_xor(mx, 32)); mx = fmaxf(mx, __shfl_xor(mx, 16));
    mx = fmaxf(mx, __shfl_xor(mx, 8));  mx = fmaxf(mx, __shfl_xor(mx, 4));
    mx = fmaxf(mx, __shfl_xor(mx, 2));  mx = fmaxf(mx, __shfl_xor(mx, 1));
    float e = __expf(v - mx);
    float sm = e;
    sm += __shfl_xor(sm, 32); sm += __shfl_xor(sm, 16); sm += __shfl_xor(sm, 8);
    sm += __shfl_xor(sm, 4);  sm += __shfl_xor(sm, 2);  sm += __shfl_xor(sm, 1);
    wgt[lane] = e / sm;
  }
  __syncthreads();

  const int d0 = tid * 4;
  float ak[4] = {0, 0, 0, 0}, av[4] = {0, 0, 0, 0};
  const u16* krow = qkv + ((size_t)b * T_ + c * 64) * 3072 + C_ + d0;
  for(int t = 0; t < 64; t++){
    float wt = wgt[t];
    short4v kv = *(const short4v*)(krow + (size_t)t * 3072);
    short4v vv = *(const short4v*)(krow + (size_t)t * 3072 + C_);
    ak[0] += wt * bf2f((u16)kv.x); ak[1] += wt * bf2f((u16)kv.y);
    ak[2] += wt * bf2f((u16)kv.z); ak[3] += wt * bf2f((u16)kv.w);
    av[0] += wt * bf2f((u16)vv.x); av[1] += wt * bf2f((u16)vv.y);
    av[2] += wt * bf2f((u16)vv.z); av[3] += wt * bf2f((u16)vv.w);
  }
  const int dh = d0 & 63, i0 = dh >> 1;
  const float* Sp = S + c * 64;
  float s0 = Sp[i0],     c0 = Sp[32 + i0];
  float s1 = Sp[i0 + 1], c1 = Sp[32 + i0 + 1];
  short4v ck4;
  ck4.x = (short)f2bf(-ak[1] * c0); ck4.y = (short)f2bf(ak[0] * s0);
  ck4.z = (short)f2bf(-ak[3] * c1); ck4.w = (short)f2bf(ak[2] * s1);
  *(short4v*)(ckr + ((size_t)b * NC_ + c) * C_ + d0) = ck4;
  // cv transposed + pre-swizzled: elem(d,c) -> [d][ ((c>>2)^(d&7))*4 + (c&3) ]
  const int h = d0 >> 6;
  u16* vctb = vct + ((size_t)b * H_ + h) * 4096;
  #pragma unroll
  for(int i = 0; i < 4; i++){
    int d = dh + i;
    int col = ((c >> 2) ^ (d & 7)) * 4 + (c & 3);
    vctb[d * 64 + col] = f2bf(av[i]);
  }
}

// ====== attention v5: swapped QK^T, P in registers, FULL-K PV, causal-structure skips ======
// 1024 blocks (b,g,h), 8 waves; wave w owns q-frags w and 15-w.
__global__ __launch_bounds__(512, 4) void attn5_kernel(
    const u16* __restrict__ qkv, const u16* __restrict__ ckr,
    const u16* __restrict__ vct, u16* __restrict__ vt,
    const float* __restrict__ S)
{
  const int bid = blockIdx.x;
  const int h = bid & 15, g = (bid >> 4) & 15, b = bid >> 8;
  const int tid = threadIdx.x;
  const int lane = tid & 63, wv = tid >> 6;
  const int l15 = lane & 15, l4 = lane >> 4;
  const int rows0 = wv, rows1 = 15 - wv;

  __shared__ u16 SH[36864];          // 72 KB
  u16* Ksh = SH;                     // [256][64] u16, 16B-granule swz ^(row&7)
  u16* Vsh = SH + 16384;             // [64][256] u16, 8B-granule swz ^(d&7)
  u16* Vcl = SH + 32768;             // [64][64]  u16, 8B-granule swz ^(d&7)

  const size_t tok0 = (size_t)b * T_ + (size_t)g * GS_;
  u16* vslot = vt + (((size_t)b * 16 + g) * 16 + h) * 16384;

  // ---- stage Vsh + Vcl via gload16 (global layouts are pre-swizzled) ----
  {
    #pragma unroll
    for(int c = 0; c < 4; c++)
      gload16(vslot + (c * 512 + tid) * 8, Vsh + c * 4096 + wv * 512);
    gload16(vct + ((size_t)b * H_ + h) * 4096 + tid * 8, Vcl + wv * 512);
  }
  // ---- stage Ksh: global -> reg -> rotary -> swizzled LDS ----
  {
    const u16* kg = qkv + tok0 * 3072 + C_ + h * 64;
    #pragma unroll
    for(int c = 0; c < 4; c++){
      int idx = c * 512 + tid;
      int row = idx >> 3;
      int s0  = idx & 7;
      short8 v = *(const short8*)(kg + (size_t)row * 3072 + s0 * 8);
      short8 rv = rot8(v, S + (g * 4 + row) * 64, s0 * 4);
      *(short8*)(Ksh + row * 64 + (s0 ^ (row & 7)) * 8) = rv;
    }
  }
  // ---- Q frags (rotated) ----
  short8 qa[2][2];
  #pragma unroll
  for(int f = 0; f < 2; f++){
    int rf = f ? rows1 : rows0;
    int qr = rf * 16 + l15;
    const u16* qp = qkv + (tok0 + qr) * 3072 + h * 64;
    #pragma unroll
    for(int kk = 0; kk < 2; kk++)
      qa[f][kk] = rot8(*(const short8*)(qp + kk * 32 + l4 * 8),
                       S + qr * 64, kk * 16 + l4 * 4);
  }
  __syncthreads();   // drains vmcnt+lgkm before any wave reads LDS

  float4v o[2][4], osum[2];
  float mst[2];
  #pragma unroll
  for(int f = 0; f < 2; f++){
    osum[f] = (float4v){0, 0, 0, 0};
    mst[f] = -1e30f;
    #pragma unroll
    for(int n = 0; n < 4; n++) o[f][n] = (float4v){0, 0, 0, 0};
  }

  // softmax update on S^T frag: st[n][r] = S[q=l15][k'=n*16+l4*4+r]
  auto sm_update = [&](int f, float4v* st){
    float mx = st[0][0];
    #pragma unroll
    for(int n = 0; n < 4; n++)
      #pragma unroll
      for(int r = 0; r < 4; r++) mx = fmaxf(mx, st[n][r]);
    mx = fmaxf(mx, __shfl_xor(mx, 16));
    mx = fmaxf(mx, __shfl_xor(mx, 32));
    float mOld = mst[f];
    if(!__all(mx <= mOld)){
      float mn = fmaxf(mOld, mx);
      float rsc = __expf(mOld - mn);
      mst[f] = mn;
      float r0 = __shfl(rsc, l4 * 4 + 0);
      float r1 = __shfl(rsc, l4 * 4 + 1);
      float r2 = __shfl(rsc, l4 * 4 + 2);
      float r3 = __shfl(rsc, l4 * 4 + 3);
      #pragma unroll
      for(int n = 0; n < 4; n++){
        o[f][n][0] *= r0; o[f][n][1] *= r1; o[f][n][2] *= r2; o[f][n][3] *= r3;
      }
      osum[f][0] *= r0; osum[f][1] *= r1; osum[f][2] *= r2; osum[f][3] *= r3;
    }
    float mm = mst[f];
    #pragma unroll
    for(int n = 0; n < 4; n++)
      #pragma unroll
      for(int r = 0; r < 4; r++) st[n][r] = __expf(st[n][r] - mm);
  };

  // FULL-K PV: pair of 16-k P-blocks per MFMA; kbpMax in {1,2} skips all-masked pairs.
  auto pv = [&](int f, float4v* st, const u16* vb, int vstride, int granBase, int kbpMax){
    #pragma unroll
    for(int kbp = 0; kbp < 2; kbp++){
      if(kbp >= kbpMax) continue;
      union{ short8 s; u32 u[4]; } pa;
      pa.u[0] = (u32)f2bf(st[2*kbp][0])   | ((u32)f2bf(st[2*kbp][1]) << 16);
      pa.u[1] = (u32)f2bf(st[2*kbp][2])   | ((u32)f2bf(st[2*kbp][3]) << 16);
      pa.u[2] = (u32)f2bf(st[2*kbp+1][0]) | ((u32)f2bf(st[2*kbp+1][1]) << 16);
      pa.u[3] = (u32)f2bf(st[2*kbp+1][2]) | ((u32)f2bf(st[2*kbp+1][3]) << 16);
      union{ short8 s; u32 u[4]; } on;
      on.u[0] = 0x3F803F80u; on.u[1] = 0x3F803F80u;
      on.u[2] = 0x3F803F80u; on.u[3] = 0x3F803F80u;
      __builtin_amdgcn_s_setprio(1);
      osum[f] = __builtin_amdgcn_mfma_f32_16x16x32_bf16(pa.s, on.s, osum[f], 0, 0, 0);
      #pragma unroll
      for(int dn = 0; dn < 4; dn++){
        int d = dn * 16 + l15;
        int gA = (granBase + (2*kbp) * 4 + l4) ^ (l15 & 7);
        int gB = (granBase + (2*kbp+1) * 4 + l4) ^ (l15 & 7);
        short4v vA = *(const short4v*)(vb + d * vstride + gA * 4);
        short4v vB = *(const short4v*)(vb + d * vstride + gB * 4);
        union{ short8 s; u32 u[4]; } vf;
        vf.u[0] = (u32)(u16)vA.x | ((u32)(u16)vA.y << 16);
        vf.u[1] = (u32)(u16)vA.z | ((u32)(u16)vA.w << 16);
        vf.u[2] = (u32)(u16)vB.x | ((u32)(u16)vB.y << 16);
        vf.u[3] = (u32)(u16)vB.z | ((u32)(u16)vB.w << 16);
        o[f][dn] = __builtin_amdgcn_mfma_f32_16x16x32_bf16(pa.s, vf.s, o[f][dn], 0, 0, 0);
      }
      __builtin_amdgcn_s_setprio(0);
    }
  };

  // ---- cluster tile (g>0): S^T rows = clusters, mask cluster >= g*4 ----
  if(g > 0){
    const int climit = g * 4;
    const int nMaxC = (climit - 1) >> 4;
    const int kbpMaxC = (nMaxC >> 1) + 1;
    #pragma unroll
    for(int f = 0; f < 2; f++){
      float4v st[4];
      #pragma unroll
      for(int n = 0; n < 4; n++) st[n] = (float4v){0, 0, 0, 0};
      #pragma unroll
      for(int kk = 0; kk < 2; kk++){
        __builtin_amdgcn_s_setprio(1);
        #pragma unroll
        for(int n = 0; n < 4; n++){
          if(n > nMaxC) continue;
          short8 kf = *(const short8*)(ckr + ((size_t)b * NC_ + n * 16 + l15) * C_
                                       + h * 64 + kk * 32 + l4 * 8);
          st[n] = __builtin_amdgcn_mfma_f32_16x16x32_bf16(kf, qa[f][kk], st[n], 0, 0, 0);
        }
        __builtin_amdgcn_s_setprio(0);
      }
      #pragma unroll
      for(int n = 0; n < 4; n++)
        #pragma unroll
        for(int r = 0; r < 4; r++){
          int col = n * 16 + l4 * 4 + r;
          st[n][r] = (col >= climit) ? -1e30f : st[n][r] * 0.125f;
        }
      sm_update(f, st);
      pv(f, st, Vcl, 64, 0, kbpMaxC);
    }
  }

  // ---- local causal tiles: K from Ksh, V from Vsh ----
  const int ktA = rows0 >> 2, ktB = rows1 >> 2;
  for(int kt = 0; kt <= ktB; kt++){
    #pragma unroll
    for(int f = 0; f < 2; f++){
      int rf = f ? rows1 : rows0;
      if(kt > (f ? ktB : ktA)) continue;
      const bool diag = (kt == (rf >> 2));
      const int nMax = diag ? (rf & 3) : 3;
      const int kbpMax = diag ? (((rf & 3) >> 1) + 1) : 2;
      float4v st[4];
      #pragma unroll
      for(int n = 0; n < 4; n++) st[n] = (float4v){0, 0, 0, 0};
      #pragma unroll
      for(int kk = 0; kk < 2; kk++){
        __builtin_amdgcn_s_setprio(1);
        #pragma unroll
        for(int n = 0; n < 4; n++){
          if(n > nMax) continue;
          int krow = kt * 64 + n * 16 + l15;
          int slot = (kk * 4 + l4) ^ (krow & 7);
          short8 kf = *(const short8*)(Ksh + krow * 64 + slot * 8);
          st[n] = __builtin_amdgcn_mfma_f32_16x16x32_bf16(kf, qa[f][kk], st[n], 0, 0, 0);
        }
        __builtin_amdgcn_s_setprio(0);
      }
      #pragma unroll
      for(int n = 0; n < 4; n++)
        #pragma unroll
        for(int r = 0; r < 4; r++){
          int col = kt * 64 + n * 16 + l4 * 4 + r;
          int q   = rf * 16 + l15;
          st[n][r] = (col > q) ? -1e30f : st[n][r] * 0.125f;
        }
      sm_update(f, st);
      pv(f, st, Vsh, 256, kt * 16, kbpMax);
    }
  }

  // ---- epilogue: normalize, write blocked y into OWN vt slot (contiguous 32KB) ----
  #pragma unroll
  for(int f = 0; f < 2; f++){
    int rf = f ? rows1 : rows0;
    #pragma unroll
    for(int r = 0; r < 4; r++){
      float inv = 1.0f / osum[f][r];
      int kq = rf * 16 + l4 * 4 + r;
      #pragma unroll
      for(int n = 0; n < 4; n++)
        vslot[kq * 64 + n * 16 + l15] = f2bf(o[f][n][r] * inv);
    }
  }
}

// ---------------- launcher ----------------
extern "C" void kernel_launch(void* const* d_in, const int* in_sizes, int n_in,
                              void* d_out, int out_size, void* d_ws, size_t ws_size,
                              hipStream_t stream)
{
  const float* x      = (const float*)d_in[0];
  const float* w_attn = (const float*)d_in[1];
  const float* b_attn = (const float*)d_in[2];
  const float* w_proj = (const float*)d_in[3];
  const float* b_proj = (const float*)d_in[4];
  const float* wasn   = (const float*)d_in[5];
  float* out = (float*)d_out;
  char* ws = (char*)d_ws;

  u16* qkv  = (u16*)(ws);                    // 100,663,296  bf16 (B,T,3C) RAW (unrotated)
  u16* xb   = (u16*)(ws + 100663296);        //  33,554,432  bf16 x
  u16* vt   = (u16*)(ws + 134217728);        //  33,554,432  [b,g,h] slots: V^T pre-swz, then y-blocked
  u16* wab  = (u16*)(ws + 167772160);        //   6,291,456
  u16* wpb  = (u16*)(ws + 174063616);        //   2,097,152
  u16* ckr  = (u16*)(ws + 176160768);        //     524,288  rotated cluster keys
  u16* vct  = (u16*)(ws + 176685056);        //     524,288  transposed cluster values (pre-swz)
  float* st = (float*)(ws + 177209344);      //      80,896  sinusoid table
  if(ws_size < 177290240) return;

  init_kernel<<<20559, 256, 0, stream>>>(x, w_attn, w_proj, xb, wab, wpb, st);
  gemm8p<1><<<768, 512, 0, stream>>>(xb, wab, b_attn, (void*)qkv, vt, 16384, 3072, 1024, 12);
  cluster_kernel<<<256, 256, 0, stream>>>(xb, wasn, qkv, st, ckr, vct);
  attn5_kernel<<<1024, 512, 0, stream>>>(qkv, ckr, vct, vt, st);
  gemm8p<2><<<256, 512, 0, stream>>>(vt, wpb, b_proj, (void*)out, nullptr, 16384, 1024, 1024, 4);
}

// Round 10
// 257.144 us; speedup vs baseline: 5.7577x; 1.0372x over previous
//
#include <hip/hip_runtime.h>
#include <stdint.h>

typedef unsigned short u16;
typedef unsigned int   u32;
typedef __attribute__((ext_vector_type(8))) short short8;
typedef __attribute__((ext_vector_type(4))) short short4v;
typedef __attribute__((ext_vector_type(4))) float float4v;
typedef __attribute__((ext_vector_type(4))) u32   uint4v;

#define B_  4
#define T_  4096
#define C_  1024
#define H_  16
#define G_  16
#define GS_ 256
#define NC_ 64

static __device__ __forceinline__ u16 f2bf(float f){
  union{float f; u32 u;} c; c.f = f;
  return (u16)((c.u + 0x7fffu + ((c.u >> 16) & 1u)) >> 16);
}
static __device__ __forceinline__ float bf2f(u16 u){
  union{u32 u; float f;} c; c.u = ((u32)u) << 16; return c.f;
}
static __device__ __forceinline__ void gload16(const void* g, void* l){
  __builtin_amdgcn_global_load_lds((__attribute__((address_space(1))) void*)g,
                                   (__attribute__((address_space(3))) void*)l, 16, 0, 0);
}
// rotary on 4 bf16 pairs: out = (-x1*cos, x0*sin); Sp = S + pos*64, i0 = pair index base
static __device__ __forceinline__ short8 rot8(short8 v, const float* Sp, int i0){
  union{ short8 s; u32 u[4]; } a, o; a.s = v;
  #pragma unroll
  for(int p = 0; p < 4; p++){
    float e0 = bf2f((u16)(a.u[p] & 0xffffu));
    float e1 = bf2f((u16)(a.u[p] >> 16));
    float sn = Sp[i0 + p], cs = Sp[32 + i0 + p];
    o.u[p] = (u32)f2bf(-e1 * cs) | ((u32)f2bf(e0 * sn) << 16);
  }
  return o.s;
}

// ---------------- merged init: fp32->bf16 for x/w_attn/w_proj + sinusoid table ----------------
__global__ __launch_bounds__(256) void init_kernel(const float* __restrict__ x,
    const float* __restrict__ wa, const float* __restrict__ wp,
    u16* __restrict__ xb, u16* __restrict__ wab, u16* __restrict__ wpb,
    float* __restrict__ S)
{
  const int bid = blockIdx.x;
  if(bid < 20480){
    int i = bid * 256 + threadIdx.x;           // float4 index in [0, 5242880)
    const float* s; u16* d; int off;
    if(i < 4194304){ s = x; d = xb; off = i; }
    else if(i < 4980736){ s = wa; d = wab; off = i - 4194304; }
    else { s = wp; d = wpb; off = i - 4980736; }
    float4v v = *(const float4v*)(s + (size_t)off * 4);
    short4v o;
    o.x = (short)f2bf(v.x); o.y = (short)f2bf(v.y);
    o.z = (short)f2bf(v.z); o.w = (short)f2bf(v.w);
    *(short4v*)(d + (size_t)off * 4) = o;
  } else {
    int pos = (bid - 20480) * 4 + (threadIdx.x >> 6);
    int d = threadIdx.x & 63;
    if(pos < 316){
      int j = d >> 1;
      float div = __expf((float)(2 * j) * (-0.14391156831212787f)); // -ln(10000)/64
      float ang = (float)pos * div;
      S[pos * 64 + d] = (d & 1) ? cosf(ang) : sinf(ang);
    }
  }
}

// ================= 8-phase 256x256 BK=64 GEMM (R7-proven: 125.5us @ K=1024) =================
// __launch_bounds__(512, 1): min-1-block request, no harmful VGPR cap (VGPR ~104).
// R8/R9 lesson: (512,4) means 4 BLOCKS/CU to hipcc -> 64-VGPR cap -> accumulator spill.
// BK=32 variant (R9) measured WORSE (134.8 vs 125.5) -> reverted to this BK=64 body.
// MODE 1: bf16 out; V-col blocks (col0>=2048) also write pre-swizzled vt slots.
// MODE 2: fp32 out; A read from blocked-y layout [b*16+g][h][256][64].
template<int MODE>
__global__ __launch_bounds__(512, 1) void gemm8p(const u16* __restrict__ A,
    const u16* __restrict__ Bm, const float* __restrict__ bias,
    void* __restrict__ Cv, u16* __restrict__ vtout, int M, int N, int K, int nbn)
{
  __shared__ u16 sA[2][2][256][32];
  __shared__ u16 sB[2][2][256][32];
  const int tid = threadIdx.x;
  const int lane = tid & 63, w = tid >> 6;
  const int l15 = lane & 15, l4 = lane >> 4;
  const int wr = w >> 2, wc = w & 3;

  const int cpx = gridDim.x >> 3;
  const int bid = blockIdx.x;
  const int swz = (bid & 7) * cpx + (bid >> 3);
  const int bm = swz / nbn, bn = swz - bm * nbn;
  const int row0 = bm * 256, col0 = bn * 256;

  float4v acc[8][4];
  #pragma unroll
  for(int m = 0; m < 8; m++)
    #pragma unroll
    for(int n = 0; n < 4; n++) acc[m][n] = (float4v){0.f, 0.f, 0.f, 0.f};

  const int srow = lane >> 2;
  const int sslot = lane & 3;

  auto stageHalfA = [&](u16* dstPlane, int ktOff){
    #pragma unroll
    for(int l = 0; l < 2; l++){
      int r = w * 32 + l * 16 + srow;
      int ss = sslot ^ ((r >> 1) & 3);
      const u16* src;
      if(MODE == 2){
        int bg = (row0 + r) >> 8;                 // b*16+g
        int hh = ktOff >> 6;
        int coff = (ktOff & 63) + ss * 8;
        src = A + ((size_t)(bg * 16 + hh)) * 16384 + (size_t)(r & 255) * 64 + coff;
      } else {
        src = A + (size_t)(row0 + r) * K + ktOff + ss * 8;
      }
      gload16(src, dstPlane + (w * 32 + l * 16) * 32);
    }
  };
  auto stageHalfB = [&](u16* dstPlane, int ktOff){
    #pragma unroll
    for(int l = 0; l < 2; l++){
      int r = w * 32 + l * 16 + srow;
      int ss = sslot ^ ((r >> 1) & 3);
      gload16(Bm + (size_t)(col0 + r) * K + ktOff + ss * 8,
              dstPlane + (w * 32 + l * 16) * 32);
    }
  };
  auto ldsReadA = [&](int d, int kk, int mh, short8* af){
    #pragma unroll
    for(int i = 0; i < 4; i++){
      int r = wr * 128 + (mh * 4 + i) * 16 + l15;
      int slot = l4 ^ ((r >> 1) & 3);
      af[i] = *(const short8*)&sA[d][kk][r][slot * 8];
    }
  };
  auto ldsReadB = [&](int d, int kk, short8* bf){
    #pragma unroll
    for(int i = 0; i < 4; i++){
      int r = wc * 64 + i * 16 + l15;
      int slot = l4 ^ ((r >> 1) & 3);
      bf[i] = *(const short8*)&sB[d][kk][r][slot * 8];
    }
  };
  auto mfma16 = [&](int mh, short8* af, short8* bf){
    __builtin_amdgcn_s_setprio(1);
    #pragma unroll
    for(int i = 0; i < 4; i++)
      #pragma unroll
      for(int n = 0; n < 4; n++)
        acc[mh * 4 + i][n] = __builtin_amdgcn_mfma_f32_16x16x32_bf16(af[i], bf[n], acc[mh * 4 + i][n], 0, 0, 0);
    __builtin_amdgcn_s_setprio(0);
  };

  stageHalfA(&sA[0][0][0][0], 0);
  stageHalfB(&sB[0][0][0][0], 0);
  stageHalfA(&sA[0][1][0][0], 32);
  stageHalfB(&sB[0][1][0][0], 32);
  asm volatile("s_waitcnt vmcnt(4)" ::: "memory");
  __builtin_amdgcn_s_barrier();

  const int nT = K >> 6;
  for(int t = 0; t < nT; t++){
    const int d = t & 1, dn = d ^ 1;
    const int ktN = (t + 1) << 6;
    const bool pf = (t + 1 < nT);
    short8 af[4], bf[4];

    ldsReadA(d, 0, 0, af); ldsReadB(d, 0, bf);
    if(pf) stageHalfA(&sA[dn][0][0][0], ktN);
    __builtin_amdgcn_s_barrier();
    mfma16(0, af, bf);
    __builtin_amdgcn_s_barrier();

    ldsReadA(d, 0, 1, af);
    if(pf) stageHalfB(&sB[dn][0][0][0], ktN);
    __builtin_amdgcn_s_barrier();
    mfma16(1, af, bf);
    if(pf) asm volatile("s_waitcnt vmcnt(4)" ::: "memory");
    else   asm volatile("s_waitcnt vmcnt(0)" ::: "memory");
    __builtin_amdgcn_s_barrier();

    ldsReadA(d, 1, 0, af); ldsReadB(d, 1, bf);
    if(pf) stageHalfA(&sA[dn][1][0][0], ktN + 32);
    __builtin_amdgcn_s_barrier();
    mfma16(0, af, bf);
    __builtin_amdgcn_s_barrier();

    ldsReadA(d, 1, 1, af);
    if(pf) stageHalfB(&sB[dn][1][0][0], ktN + 32);
    __builtin_amdgcn_s_barrier();
    mfma16(1, af, bf);
    if(pf) asm volatile("s_waitcnt vmcnt(4)" ::: "memory");
    __builtin_amdgcn_s_barrier();
  }

  // ---- epilogue ----
  #pragma unroll
  for(int m = 0; m < 8; m++){
    #pragma unroll
    for(int n = 0; n < 4; n++){
      int col = col0 + wc * 64 + n * 16 + l15;
      float bv = bias[col];
      #pragma unroll
      for(int j = 0; j < 4; j++){
        int row = row0 + wr * 128 + m * 16 + l4 * 4 + j;
        float v = acc[m][n][j] + bv;
        acc[m][n][j] = v;
        if(MODE == 1) ((u16*)Cv)[(size_t)row * N + col] = f2bf(v);
        else          ((float*)Cv)[(size_t)row * N + col] = v;
      }
    }
  }
  // fused vt write: V-col blocks cover exactly one (b,g) x 4 heads
  if(MODE == 1 && col0 >= 2048){
    const int b = row0 >> 12, g = (row0 >> 8) & 15;
    const int h = ((col0 - 2048) >> 6) + wc;
    u32* vbase = (u32*)(vtout + (((size_t)(b * 16 + g)) * 16 + h) * 16384);
    #pragma unroll
    for(int n = 0; n < 4; n++){
      int d = n * 16 + l15;
      #pragma unroll
      for(int m = 0; m < 8; m++){
        int kb = (wr * 128 + m * 16 + l4 * 4) >> 2;   // k>>2 (j<4)
        int col2 = (kb ^ (d & 7)) << 1;
        u32 lo = (u32)f2bf(acc[m][n][0]) | ((u32)f2bf(acc[m][n][1]) << 16);
        u32 hi = (u32)f2bf(acc[m][n][2]) | ((u32)f2bf(acc[m][n][3]) << 16);
        vbase[d * 128 + col2]     = lo;
        vbase[d * 128 + col2 + 1] = hi;
      }
    }
  }
}

// ---------------- cluster assign softmax + ck (rotated) / cv (transposed, PRE-SWIZZLED) ----------------
// logits from bf16 xb; weights/accum fp32.
__global__ __launch_bounds__(256) void cluster_kernel(
    const u16* __restrict__ xb, const float* __restrict__ wasn,
    const u16* __restrict__ qkv, const float* __restrict__ S,
    u16* __restrict__ ckr, u16* __restrict__ vct)
{
  const int bc = blockIdx.x;
  const int c = bc & 63, b = bc >> 6;
  const int tid = threadIdx.x;
  const int lane = tid & 63, wv = tid >> 6;
  __shared__ float wgt[64];

  const u16* xrow = xb + ((size_t)b * T_ + c * 64) * C_;
  float4v wa4[4];
  #pragma unroll
  for(int ch = 0; ch < 4; ch++)
    wa4[ch] = *(const float4v*)(wasn + c * C_ + ch * 256 + lane * 4);

  for(int it = 0; it < 16; it++){
    int t = it * 4 + wv;
    const u16* xr = xrow + (size_t)t * C_;
    float p = 0.f;
    #pragma unroll
    for(int ch = 0; ch < 4; ch++){
      short4v xv = *(const short4v*)(xr + ch * 256 + lane * 4);
      p += bf2f((u16)xv.x) * wa4[ch].x + bf2f((u16)xv.y) * wa4[ch].y
         + bf2f((u16)xv.z) * wa4[ch].z + bf2f((u16)xv.w) * wa4[ch].w;
    }
    p += __shfl_down(p, 32); p += __shfl_down(p, 16); p += __shfl_down(p, 8);
    p += __shfl_down(p, 4);  p += __shfl_down(p, 2);  p += __shfl_down(p, 1);
    if(lane == 0) wgt[t] = p;
  }
  __syncthreads();
  if(wv == 0){
    float v = wgt[lane];
    float mx = v;
    mx = fmaxf(mx, __shfl_xor(mx, 32)); mx = fmaxf(mx, __shfl_xor(mx, 16));
    mx = fmaxf(mx, __shfl_xor(mx, 8));  mx = fmaxf(mx, __shfl_xor(mx, 4));
    mx = fmaxf(mx, __shfl_xor(mx, 2));  mx = fmaxf(mx, __shfl_xor(mx, 1));
    float e = __expf(v - mx);
    float sm = e;
    sm += __shfl_xor(sm, 32); sm += __shfl_xor(sm, 16); sm += __shfl_xor(sm, 8);
    sm += __shfl_xor(sm, 4);  sm += __shfl_xor(sm, 2);  sm += __shfl_xor(sm, 1);
    wgt[lane] = e / sm;
  }
  __syncthreads();

  const int d0 = tid * 4;
  float ak[4] = {0, 0, 0, 0}, av[4] = {0, 0, 0, 0};
  const u16* krow = qkv + ((size_t)b * T_ + c * 64) * 3072 + C_ + d0;
  for(int t = 0; t < 64; t++){
    float wt = wgt[t];
    short4v kv = *(const short4v*)(krow + (size_t)t * 3072);
    short4v vv = *(const short4v*)(krow + (size_t)t * 3072 + C_);
    ak[0] += wt * bf2f((u16)kv.x); ak[1] += wt * bf2f((u16)kv.y);
    ak[2] += wt * bf2f((u16)kv.z); ak[3] += wt * bf2f((u16)kv.w);
    av[0] += wt * bf2f((u16)vv.x); av[1] += wt * bf2f((u16)vv.y);
    av[2] += wt * bf2f((u16)vv.z); av[3] += wt * bf2f((u16)vv.w);
  }
  const int dh = d0 & 63, i0 = dh >> 1;
  const float* Sp = S + c * 64;
  float s0 = Sp[i0],     c0 = Sp[32 + i0];
  float s1 = Sp[i0 + 1], c1 = Sp[32 + i0 + 1];
  short4v ck4;
  ck4.x = (short)f2bf(-ak[1] * c0); ck4.y = (short)f2bf(ak[0] * s0);
  ck4.z = (short)f2bf(-ak[3] * c1); ck4.w = (short)f2bf(ak[2] * s1);
  *(short4v*)(ckr + ((size_t)b * NC_ + c) * C_ + d0) = ck4;
  // cv transposed + pre-swizzled: elem(d,c) -> [d][ ((c>>2)^(d&7))*4 + (c&3) ]
  const int h = d0 >> 6;
  u16* vctb = vct + ((size_t)b * H_ + h) * 4096;
  #pragma unroll
  for(int i = 0; i < 4; i++){
    int d = dh + i;
    int col = ((c >> 2) ^ (d & 7)) * 4 + (c & 3);
    vctb[d * 64 + col] = f2bf(av[i]);
  }
}

// ====== attention v5: swapped QK^T, P in registers, FULL-K PV, causal-structure skips ======
// 1024 blocks (b,g,h), 8 waves; wave w owns q-frags w and 15-w.
// __launch_bounds__(512) with NO min-blocks arg: R8 proved (512,4) means 4 blocks/CU to
// hipcc -> 64-VGPR cap -> this kernel's ~130-reg state was silently spilling to scratch.
__global__ __launch_bounds__(512) void attn5_kernel(
    const u16* __restrict__ qkv, const u16* __restrict__ ckr,
    const u16* __restrict__ vct, u16* __restrict__ vt,
    const float* __restrict__ S)
{
  const int bid = blockIdx.x;
  const int h = bid & 15, g = (bid >> 4) & 15, b = bid >> 8;
  const int tid = threadIdx.x;
  const int lane = tid & 63, wv = tid >> 6;
  const int l15 = lane & 15, l4 = lane >> 4;
  const int rows0 = wv, rows1 = 15 - wv;

  __shared__ u16 SH[36864];          // 72 KB
  u16* Ksh = SH;                     // [256][64] u16, 16B-granule swz ^(row&7)
  u16* Vsh = SH + 16384;             // [64][256] u16, 8B-granule swz ^(d&7)
  u16* Vcl = SH + 32768;             // [64][64]  u16, 8B-granule swz ^(d&7)

  const size_t tok0 = (size_t)b * T_ + (size_t)g * GS_;
  u16* vslot = vt + (((size_t)b * 16 + g) * 16 + h) * 16384;

  // ---- stage Vsh + Vcl via gload16 (global layouts are pre-swizzled) ----
  {
    #pragma unroll
    for(int c = 0; c < 4; c++)
      gload16(vslot + (c * 512 + tid) * 8, Vsh + c * 4096 + wv * 512);
    gload16(vct + ((size_t)b * H_ + h) * 4096 + tid * 8, Vcl + wv * 512);
  }
  // ---- stage Ksh: global -> reg -> rotary -> swizzled LDS ----
  {
    const u16* kg = qkv + tok0 * 3072 + C_ + h * 64;
    #pragma unroll
    for(int c = 0; c < 4; c++){
      int idx = c * 512 + tid;
      int row = idx >> 3;
      int s0  = idx & 7;
      short8 v = *(const short8*)(kg + (size_t)row * 3072 + s0 * 8);
      short8 rv = rot8(v, S + (g * 4 + row) * 64, s0 * 4);
      *(short8*)(Ksh + row * 64 + (s0 ^ (row & 7)) * 8) = rv;
    }
  }
  // ---- Q frags (rotated) ----
  short8 qa[2][2];
  #pragma unroll
  for(int f = 0; f < 2; f++){
    int rf = f ? rows1 : rows0;
    int qr = rf * 16 + l15;
    const u16* qp = qkv + (tok0 + qr) * 3072 + h * 64;
    #pragma unroll
    for(int kk = 0; kk < 2; kk++)
      qa[f][kk] = rot8(*(const short8*)(qp + kk * 32 + l4 * 8),
                       S + qr * 64, kk * 16 + l4 * 4);
  }
  __syncthreads();   // drains vmcnt+lgkm before any wave reads LDS

  float4v o[2][4], osum[2];
  float mst[2];
  #pragma unroll
  for(int f = 0; f < 2; f++){
    osum[f] = (float4v){0, 0, 0, 0};
    mst[f] = -1e30f;
    #pragma unroll
    for(int n = 0; n < 4; n++) o[f][n] = (float4v){0, 0, 0, 0};
  }

  // softmax update on S^T frag: st[n][r] = S[q=l15][k'=n*16+l4*4+r]
  auto sm_update = [&](int f, float4v* st){
    float mx = st[0][0];
    #pragma unroll
    for(int n = 0; n < 4; n++)
      #pragma unroll
      for(int r = 0; r < 4; r++) mx = fmaxf(mx, st[n][r]);
    mx = fmaxf(mx, __shfl_xor(mx, 16));
    mx = fmaxf(mx, __shfl_xor(mx, 32));
    float mOld = mst[f];
    if(!__all(mx <= mOld)){
      float mn = fmaxf(mOld, mx);
      float rsc = __expf(mOld - mn);
      mst[f] = mn;
      float r0 = __shfl(rsc, l4 * 4 + 0);
      float r1 = __shfl(rsc, l4 * 4 + 1);
      float r2 = __shfl(rsc, l4 * 4 + 2);
      float r3 = __shfl(rsc, l4 * 4 + 3);
      #pragma unroll
      for(int n = 0; n < 4; n++){
        o[f][n][0] *= r0; o[f][n][1] *= r1; o[f][n][2] *= r2; o[f][n][3] *= r3;
      }
      osum[f][0] *= r0; osum[f][1] *= r1; osum[f][2] *= r2; osum[f][3] *= r3;
    }
    float mm = mst[f];
    #pragma unroll
    for(int n = 0; n < 4; n++)
      #pragma unroll
      for(int r = 0; r < 4; r++) st[n][r] = __expf(st[n][r] - mm);
  };

  // FULL-K PV: pair of 16-k P-blocks per MFMA; kbpMax in {1,2} skips all-masked pairs.
  auto pv = [&](int f, float4v* st, const u16* vb, int vstride, int granBase, int kbpMax){
    #pragma unroll
    for(int kbp = 0; kbp < 2; kbp++){
      if(kbp >= kbpMax) continue;
      union{ short8 s; u32 u[4]; } pa;
      pa.u[0] = (u32)f2bf(st[2*kbp][0])   | ((u32)f2bf(st[2*kbp][1]) << 16);
      pa.u[1] = (u32)f2bf(st[2*kbp][2])   | ((u32)f2bf(st[2*kbp][3]) << 16);
      pa.u[2] = (u32)f2bf(st[2*kbp+1][0]) | ((u32)f2bf(st[2*kbp+1][1]) << 16);
      pa.u[3] = (u32)f2bf(st[2*kbp+1][2]) | ((u32)f2bf(st[2*kbp+1][3]) << 16);
      union{ short8 s; u32 u[4]; } on;
      on.u[0] = 0x3F803F80u; on.u[1] = 0x3F803F80u;
      on.u[2] = 0x3F803F80u; on.u[3] = 0x3F803F80u;
      __builtin_amdgcn_s_setprio(1);
      osum[f] = __builtin_amdgcn_mfma_f32_16x16x32_bf16(pa.s, on.s, osum[f], 0, 0, 0);
      #pragma unroll
      for(int dn = 0; dn < 4; dn++){
        int d = dn * 16 + l15;
        int gA = (granBase + (2*kbp) * 4 + l4) ^ (l15 & 7);
        int gB = (granBase + (2*kbp+1) * 4 + l4) ^ (l15 & 7);
        short4v vA = *(const short4v*)(vb + d * vstride + gA * 4);
        short4v vB = *(const short4v*)(vb + d * vstride + gB * 4);
        union{ short8 s; u32 u[4]; } vf;
        vf.u[0] = (u32)(u16)vA.x | ((u32)(u16)vA.y << 16);
        vf.u[1] = (u32)(u16)vA.z | ((u32)(u16)vA.w << 16);
        vf.u[2] = (u32)(u16)vB.x | ((u32)(u16)vB.y << 16);
        vf.u[3] = (u32)(u16)vB.z | ((u32)(u16)vB.w << 16);
        o[f][dn] = __builtin_amdgcn_mfma_f32_16x16x32_bf16(pa.s, vf.s, o[f][dn], 0, 0, 0);
      }
      __builtin_amdgcn_s_setprio(0);
    }
  };

  // ---- cluster tile (g>0): S^T rows = clusters, mask cluster >= g*4 ----
  if(g > 0){
    const int climit = g * 4;
    const int nMaxC = (climit - 1) >> 4;
    const int kbpMaxC = (nMaxC >> 1) + 1;
    #pragma unroll
    for(int f = 0; f < 2; f++){
      float4v st[4];
      #pragma unroll
      for(int n = 0; n < 4; n++) st[n] = (float4v){0, 0, 0, 0};
      #pragma unroll
      for(int kk = 0; kk < 2; kk++){
        __builtin_amdgcn_s_setprio(1);
        #pragma unroll
        for(int n = 0; n < 4; n++){
          if(n > nMaxC) continue;
          short8 kf = *(const short8*)(ckr + ((size_t)b * NC_ + n * 16 + l15) * C_
                                       + h * 64 + kk * 32 + l4 * 8);
          st[n] = __builtin_amdgcn_mfma_f32_16x16x32_bf16(kf, qa[f][kk], st[n], 0, 0, 0);
        }
        __builtin_amdgcn_s_setprio(0);
      }
      #pragma unroll
      for(int n = 0; n < 4; n++)
        #pragma unroll
        for(int r = 0; r < 4; r++){
          int col = n * 16 + l4 * 4 + r;
          st[n][r] = (col >= climit) ? -1e30f : st[n][r] * 0.125f;
        }
      sm_update(f, st);
      pv(f, st, Vcl, 64, 0, kbpMaxC);
    }
  }

  // ---- local causal tiles: K from Ksh, V from Vsh ----
  const int ktA = rows0 >> 2, ktB = rows1 >> 2;
  for(int kt = 0; kt <= ktB; kt++){
    #pragma unroll
    for(int f = 0; f < 2; f++){
      int rf = f ? rows1 : rows0;
      if(kt > (f ? ktB : ktA)) continue;
      const bool diag = (kt == (rf >> 2));
      const int nMax = diag ? (rf & 3) : 3;
      const int kbpMax = diag ? (((rf & 3) >> 1) + 1) : 2;
      float4v st[4];
      #pragma unroll
      for(int n = 0; n < 4; n++) st[n] = (float4v){0, 0, 0, 0};
      #pragma unroll
      for(int kk = 0; kk < 2; kk++){
        __builtin_amdgcn_s_setprio(1);
        #pragma unroll
        for(int n = 0; n < 4; n++){
          if(n > nMax) continue;
          int krow = kt * 64 + n * 16 + l15;
          int slot = (kk * 4 + l4) ^ (krow & 7);
          short8 kf = *(const short8*)(Ksh + krow * 64 + slot * 8);
          st[n] = __builtin_amdgcn_mfma_f32_16x16x32_bf16(kf, qa[f][kk], st[n], 0, 0, 0);
        }
        __builtin_amdgcn_s_setprio(0);
      }
      #pragma unroll
      for(int n = 0; n < 4; n++)
        #pragma unroll
        for(int r = 0; r < 4; r++){
          int col = kt * 64 + n * 16 + l4 * 4 + r;
          int q   = rf * 16 + l15;
          st[n][r] = (col > q) ? -1e30f : st[n][r] * 0.125f;
        }
      sm_update(f, st);
      pv(f, st, Vsh, 256, kt * 16, kbpMax);
    }
  }

  // ---- epilogue: normalize, write blocked y into OWN vt slot (contiguous 32KB) ----
  #pragma unroll
  for(int f = 0; f < 2; f++){
    int rf = f ? rows1 : rows0;
    #pragma unroll
    for(int r = 0; r < 4; r++){
      float inv = 1.0f / osum[f][r];
      int kq = rf * 16 + l4 * 4 + r;
      #pragma unroll
      for(int n = 0; n < 4; n++)
        vslot[kq * 64 + n * 16 + l15] = f2bf(o[f][n][r] * inv);
    }
  }
}

// ---------------- launcher ----------------
extern "C" void kernel_launch(void* const* d_in, const int* in_sizes, int n_in,
                              void* d_out, int out_size, void* d_ws, size_t ws_size,
                              hipStream_t stream)
{
  const float* x      = (const float*)d_in[0];
  const float* w_attn = (const float*)d_in[1];
  const float* b_attn = (const float*)d_in[2];
  const float* w_proj = (const float*)d_in[3];
  const float* b_proj = (const float*)d_in[4];
  const float* wasn   = (const float*)d_in[5];
  float* out = (float*)d_out;
  char* ws = (char*)d_ws;

  u16* qkv  = (u16*)(ws);                    // 100,663,296  bf16 (B,T,3C) RAW (unrotated)
  u16* xb   = (u16*)(ws + 100663296);        //  33,554,432  bf16 x
  u16* vt   = (u16*)(ws + 134217728);        //  33,554,432  [b,g,h] slots: V^T pre-swz, then y-blocked
  u16* wab  = (u16*)(ws + 167772160);        //   6,291,456
  u16* wpb  = (u16*)(ws + 174063616);        //   2,097,152
  u16* ckr  = (u16*)(ws + 176160768);        //     524,288  rotated cluster keys
  u16* vct  = (u16*)(ws + 176685056);        //     524,288  transposed cluster values (pre-swz)
  float* st = (float*)(ws + 177209344);      //      80,896  sinusoid table
  if(ws_size < 177290240) return;

  init_kernel<<<20559, 256, 0, stream>>>(x, w_attn, w_proj, xb, wab, wpb, st);
  gemm8p<1><<<768, 512, 0, stream>>>(xb, wab, b_attn, (void*)qkv, vt, 16384, 3072, 1024, 12);
  cluster_kernel<<<256, 256, 0, stream>>>(xb, wasn, qkv, st, ckr, vct);
  attn5_kernel<<<1024, 512, 0, stream>>>(qkv, ckr, vct, vt, st);
  gemm8p<2><<<256, 512, 0, stream>>>(vt, wpb, b_proj, (void*)out, nullptr, 16384, 1024, 1024, 4);
}